// Round 7
// baseline (987.036 us; speedup 1.0000x reference)
//
#include <hip/hip_runtime.h>
#include <hip/hip_bf16.h>

#define HWSZ 12544   // 112*112
#define WDIM 112
#define CIN  128
#define NPIX 25088   // B*HWSZ, B=2
#define VTROW 6272   // 112*56 = one (b,parity,ch) plane of vt (hw>>1 indexed)
#define VTOFF (2 * (size_t)NPIX * 64)   // vt base in qkv (u16 units)

typedef __attribute__((ext_vector_type(8))) short          short8;
typedef __attribute__((ext_vector_type(4))) float          float4v;
typedef __attribute__((ext_vector_type(4))) unsigned short ushort4v;

#define AS1 __attribute__((address_space(1)))
#define AS3 __attribute__((address_space(3)))

__device__ __forceinline__ void gload_lds16(const void* g, void* l) {
    __builtin_amdgcn_global_load_lds((const AS1 unsigned int*)g,
                                     (AS3 unsigned int*)l, 16, 0, 0);
}

// keep values live without cost (rule #17)
__device__ __forceinline__ void sinkf(float a, float b, float c, float d) {
    asm volatile("" :: "v"(a), "v"(b), "v"(c), "v"(d));
}
__device__ __forceinline__ void sink4(float4v v) { sinkf(v[0], v[1], v[2], v[3]); }
__device__ __forceinline__ void sink8(short8 v) {
    float4v f = __builtin_bit_cast(float4v, v);
    sink4(f);
}

// NATTEN window start for K=7, D=2
__device__ __forceinline__ int window_start7x2(int idx, int L) {
    int ni = idx - 6;
    int imodd = idx & 1;
    int a = (L >> 1) << 1;
    int bb = L - a;
    int right = (imodd < bb) ? (L - bb + imodd - 12) : (a + imodd - 14);
    if (ni < 0) return imodd;
    if (idx + 6 >= L) return right;
    return ni;
}

__device__ __forceinline__ unsigned short f2bf(float f) {
    __hip_bfloat16 h = __float2bfloat16(f);
    return *(unsigned short*)&h;
}

// ---------------------------------------------------------------------------
// Projection GEMM — unchanged (rep-probe bound: < 5.2 us/launch).
// ---------------------------------------------------------------------------
__global__ __launch_bounds__(256) void proj_mfma(
    const float* __restrict__ x,
    const float* __restrict__ Wq, const float* __restrict__ bq,
    const float* __restrict__ Wk, const float* __restrict__ bk,
    const float* __restrict__ Wv, const float* __restrict__ bv,
    unsigned short* __restrict__ qbuf)
{
    __shared__ __align__(16) unsigned short wsb[3][64][136];
    __shared__ __align__(16) unsigned short trans[64 * 80];

    const int t = threadIdx.x, lane = t & 63, wv = t >> 6, quad = lane >> 4;
    const int col = lane & 15;

    const int tile = blockIdx.x;
    const int pix0 = tile * 64;
    const int b    = tile / 196;
    const int hw0  = pix0 - b * HWSZ;
    const float* xb = x + (size_t)b * CIN * HWSZ;

    #pragma unroll
    for (int m = 0; m < 3; ++m) {
        const float* Wm = (m == 0) ? Wq : (m == 1) ? Wk : Wv;
        #pragma unroll
        for (int i = 0; i < 8; ++i) {
            int u = t + 256 * i;
            int o = u >> 5, cq = (u & 31) * 4;
            float4 w4 = *(const float4*)&Wm[o * 128 + cq];
            ushort4v s4 = { f2bf(w4.x), f2bf(w4.y), f2bf(w4.z), f2bf(w4.w) };
            *(ushort4v*)&wsb[m][o][cq] = s4;
        }
    }

    const int hwpx = hw0 + wv * 16 + col;
    short8 af[4];
    #pragma unroll
    for (int kc = 0; kc < 4; ++kc) {
        #pragma unroll
        for (int j = 0; j < 8; ++j) {
            int c = kc * 32 + quad * 8 + j;
            af[kc][j] = (short)f2bf(xb[(size_t)c * HWSZ + hwpx]);
        }
    }
    __syncthreads();

    float4v acc[3][4];
    #pragma unroll
    for (int m = 0; m < 3; ++m)
        #pragma unroll
        for (int nt = 0; nt < 4; ++nt)
            acc[m][nt] = (float4v){0, 0, 0, 0};

    #pragma unroll
    for (int kc = 0; kc < 4; ++kc) {
        #pragma unroll
        for (int m = 0; m < 3; ++m) {
            #pragma unroll
            for (int nt = 0; nt < 4; ++nt) {
                short8 bfv = *(const short8*)&wsb[m][nt * 16 + col][kc * 32 + quad * 8];
                acc[m][nt] = __builtin_amdgcn_mfma_f32_16x16x32_bf16(af[kc], bfv, acc[m][nt], 0, 0, 0);
            }
        }
    }
    __syncthreads();

    #pragma unroll
    for (int m = 0; m < 2; ++m) {
        const float scale = (m == 0) ? 0.125f : 1.0f;
        const float* bm = (m == 0) ? bq : bk;
        #pragma unroll
        for (int nt = 0; nt < 4; ++nt) {
            float bias = bm[nt * 16 + col];
            #pragma unroll
            for (int r = 0; r < 4; ++r) {
                int px = wv * 16 + quad * 4 + r;
                trans[px * 80 + nt * 16 + col] = f2bf((acc[m][nt][r] + bias) * scale);
            }
        }
        __syncthreads();
        unsigned short* outm = qbuf + (size_t)m * NPIX * 64;
        const int tpx = t >> 2, chunk = t & 3;
        const unsigned short* src = &trans[tpx * 80 + chunk * 16];
        unsigned short* dst = outm + (size_t)(pix0 + tpx) * 64 + chunk * 16;
        *(short8*)(dst)     = *(const short8*)(src);
        *(short8*)(dst + 8) = *(const short8*)(src + 8);
        __syncthreads();
    }

    {
        #pragma unroll
        for (int nt = 0; nt < 4; ++nt) {
            int ch = nt * 16 + col;
            float bias = bv[ch];
            #pragma unroll
            for (int r = 0; r < 4; ++r) {
                int px = wv * 16 + quad * 4 + r;
                trans[ch * 80 + (px & 1) * 40 + (px >> 1)] = f2bf(acc[2][nt][r] + bias);
            }
        }
        __syncthreads();
        unsigned short* vt = qbuf + VTOFF;
        const int ch = t >> 2, parity = (t >> 1) & 1, half = t & 1;
        const unsigned short* src = &trans[ch * 80 + parity * 40 + half * 16];
        unsigned short* dst = vt + (size_t)((b * 2 + parity) * 64 + ch) * VTROW
                            + (hw0 >> 1) + half * 16;
        *(short8*)(dst)     = *(const short8*)(src);
        *(short8*)(dst + 8) = *(const short8*)(src + 8);
    }
}

// ---------------------------------------------------------------------------
// Attention body, phase-ablatable.
// MODE 0: full (writes out; bit-idempotent)
// MODE 1: loads only (Q, vpre, K-stage, vmcnt) -> sink
// MODE 2: + scores/mask/exp/shuffle-sums -> sink      (no barrier crossed)
// MODE 3: + ps write, barriers, rinv, PV MFMA -> sink (no epilogue/out)
// ---------------------------------------------------------------------------
template<int MODE>
__device__ __forceinline__ void attn_body_t(
    const unsigned short* __restrict__ qkv, float* __restrict__ out, int bx)
{
    __shared__ __align__(16) unsigned char slab[4][14336];
    __shared__ __align__(16) float sums_lds[2][2][16];

    const int tid  = threadIdx.x;
    const int lane = tid & 63, wid = tid >> 6;
    const int g    = wid & 1;
    const int vh   = wid >> 1;
    const int quad = lane >> 4, col = lane & 15;

    const int xcd  = bx & 7;
    const int idx  = bx >> 3;
    const int h    = xcd * 14 + (idx >> 3);
    const int b    = (idx >> 2) & 1;
    const int sub  = idx & 3;
    const int pb   = (sub < 3) ? sub * 16 : 40;

    const int hs  = window_start7x2(h, WDIM);
    const int ws0 = window_start7x2(2 * pb + g, WDIM);
    const int cb0 = (ws0 >> 1) & ~7;
    const int pixbase = b * HWSZ;

    const unsigned short* qg = qkv;
    const unsigned short* kg = qkv + (size_t)NPIX * 64;
    const unsigned short* vt = qkv + VTOFF + (size_t)(b * 2 + g) * 64 * VTROW;

    unsigned short* ps_g   = (unsigned short*)slab[g];
    unsigned char*  myslab = slab[wid];

    const int qpix = pixbase + h * WDIM + 2 * (pb + col) + g;
    short8 af0 = *(const short8*)(qg + (size_t)qpix * 64 + quad * 8);
    short8 af1 = *(const short8*)(qg + (size_t)qpix * 64 + 32 + quad * 8);

    int cbr[4];
    #pragma unroll
    for (int r = 0; r < 4; ++r)
        cbr[r] = (window_start7x2(2 * (pb + quad * 4 + r) + g, WDIM) >> 1) - cb0;

    int rowoff[7];
    #pragma unroll
    for (int kc = 0; kc < 7; ++kc) {
        int u8 = kc * 32 + quad * 8;
        rowoff[kc] = (hs + 2 * (u8 >> 5)) * 56 + cb0 + (u8 & 31);
    }
    short8 vpre[7][2];
    #pragma unroll
    for (int kc = 0; kc < 7; ++kc)
        #pragma unroll
        for (int ntl = 0; ntl < 2; ++ntl)
            vpre[kc][ntl] = *(const short8*)
                (vt + (size_t)(vh * 32 + ntl * 16 + col) * VTROW + rowoff[kc]);

    #pragma unroll
    for (int ntl = 0; ntl < 7; ++ntl) {
        int u = (vh * 7 + ntl) * 16 + col;
        int i = u >> 5, c = u & 31;
        int kw = 2 * (cb0 + c) + g; kw = (kw > 111) ? 111 : kw;
        int kp = pixbase + (hs + 2 * i) * WDIM + kw;
        const unsigned short* gs = kg + (size_t)kp * 64 + quad * 8;
        gload_lds16(gs,      myslab + ntl * 2048);
        gload_lds16(gs + 32, myslab + ntl * 2048 + 1024);
    }

    asm volatile("s_waitcnt vmcnt(0)" ::: "memory");
    __builtin_amdgcn_sched_barrier(0);

    if constexpr (MODE == 1) {
        sink8(af0); sink8(af1);
        #pragma unroll
        for (int kc = 0; kc < 7; ++kc) { sink8(vpre[kc][0]); sink8(vpre[kc][1]); }
        return;
    }

    float4v S[7];
    #pragma unroll
    for (int ntl = 0; ntl < 7; ++ntl) {
        short8 b0 = *(const short8*)(myslab + ntl * 2048 + lane * 16);
        short8 b1 = *(const short8*)(myslab + ntl * 2048 + 1024 + lane * 16);
        float4v a = {0, 0, 0, 0};
        a = __builtin_amdgcn_mfma_f32_16x16x32_bf16(af0, b0, a, 0, 0, 0);
        a = __builtin_amdgcn_mfma_f32_16x16x32_bf16(af1, b1, a, 0, 0, 0);
        int u = (vh * 7 + ntl) * 16 + col;
        int c = u & 31;
        bool colok = (cb0 + c <= 55);
        #pragma unroll
        for (int r = 0; r < 4; ++r) {
            bool valid = colok && ((unsigned)(c - cbr[r]) < 7u);
            S[ntl][r] = valid ? a[r] : -1e30f;
        }
    }

    float psum[4];
    #pragma unroll
    for (int r = 0; r < 4; ++r) {
        float sum = 0.0f;
        #pragma unroll
        for (int ntl = 0; ntl < 7; ++ntl) {
            float e = __expf(S[ntl][r]);
            S[ntl][r] = e;
            sum += e;
        }
        #pragma unroll
        for (int msk = 1; msk < 16; msk <<= 1)
            sum += __shfl_xor(sum, msk, 64);
        psum[r] = sum;
    }

    if constexpr (MODE == 2) {
        #pragma unroll
        for (int ntl = 0; ntl < 7; ++ntl) sink4(S[ntl]);
        sinkf(psum[0], psum[1], psum[2], psum[3]);
        #pragma unroll
        for (int kc = 0; kc < 7; ++kc) { sink8(vpre[kc][0]); sink8(vpre[kc][1]); }
        return;
    }

    __syncthreads();   // slab score-reads done; slabs 0/1 reusable as ps

    #pragma unroll
    for (int r = 0; r < 4; ++r) {
        int row = quad * 4 + r;
        #pragma unroll
        for (int ntl = 0; ntl < 7; ++ntl)
            ps_g[row * 232 + (vh * 7 + ntl) * 16 + col] = f2bf(S[ntl][r]);
    }
    if (col == 0) {
        #pragma unroll
        for (int r = 0; r < 4; ++r)
            sums_lds[g][vh][quad * 4 + r] = psum[r];
    }
    __syncthreads();

    float rinv[4];
    #pragma unroll
    for (int r = 0; r < 4; ++r) {
        int row = quad * 4 + r;
        rinv[r] = 1.0f / (sums_lds[g][0][row] + sums_lds[g][1][row]);
    }

    float4v O[2] = {{0,0,0,0},{0,0,0,0}};
    #pragma unroll
    for (int kc = 0; kc < 7; ++kc) {
        short8 pa = *(const short8*)&ps_g[col * 232 + kc * 32 + quad * 8];
        #pragma unroll
        for (int ntl = 0; ntl < 2; ++ntl)
            O[ntl] = __builtin_amdgcn_mfma_f32_16x16x32_bf16(pa, vpre[kc][ntl], O[ntl], 0, 0, 0);
    }

    if constexpr (MODE == 3) {
        sink4(O[0]); sink4(O[1]);
        sinkf(rinv[0], rinv[1], rinv[2], rinv[3]);
        return;   // rep-boundary barrier orders ps reads vs next-rep staging
    }

    float* lds_out = (float*)slab[2];
    #pragma unroll
    for (int ntl = 0; ntl < 2; ++ntl) {
        int ch = vh * 32 + ntl * 16 + col;
        #pragma unroll
        for (int r = 0; r < 4; ++r)
            lds_out[ch * 36 + 2 * (quad * 4 + r) + g] = O[ntl][r] * rinv[r];
    }
    __syncthreads();

    {
        const int ch = tid >> 2, q4 = tid & 3;
        float* ob = out + (size_t)(b * 64 + ch) * HWSZ + h * WDIM + 2 * pb + q4 * 8;
        const float* src = &lds_out[ch * 36 + q4 * 8];
        *(float4*)(ob)     = *(const float4*)(src);
        *(float4*)(ob + 4) = *(const float4*)(src + 4);
    }
}

__global__ __launch_bounds__(256) void attn_mfma(
    const unsigned short* __restrict__ qkv, float* __restrict__ out)
{
    attn_body_t<0>(qkv, out, blockIdx.x);
}

// DIAGNOSTIC phase probes: laundered pointers defeat LICM; rep-boundary
// barrier orders cross-rep slab reuse. MODE 1/2/3 write nothing global.
template<int MODE, int REPS>
__global__ __launch_bounds__(256) void attn_probe(
    const unsigned short* __restrict__ qkv, float* __restrict__ out)
{
    for (int rep = 0; rep < REPS; ++rep) {
        const unsigned short* qr = qkv;
        float* orr = out;
        asm volatile("" : "+v"(qr), "+v"(orr) :: "memory");
        attn_body_t<MODE>(qr, orr, blockIdx.x);
        __syncthreads();
    }
}

// ---------------------------------------------------------------------------
extern "C" void kernel_launch(void* const* d_in, const int* in_sizes, int n_in,
                              void* d_out, int out_size, void* d_ws, size_t ws_size,
                              hipStream_t stream) {
    const float* x  = (const float*)d_in[0];
    const float* Wq = (const float*)d_in[1];
    const float* bq = (const float*)d_in[2];
    const float* Wk = (const float*)d_in[3];
    const float* bk = (const float*)d_in[4];
    const float* Wv = (const float*)d_in[5];
    const float* bv = (const float*)d_in[6];
    float* out = (float*)d_out;

    unsigned short* qkv = (unsigned short*)d_ws;

    // real pipeline
    proj_mfma<<<dim3(392), dim3(256), 0, stream>>>(x, Wq, bq, Wk, bk, Wv, bv, qkv);
    attn_mfma<<<dim3(896), dim3(256), 0, stream>>>(qkv, out);

    // phase-ablation probes (idempotent; decode via top-5 dur rows)
    attn_probe<0, 8><<<dim3(896), dim3(256), 0, stream>>>(qkv, out);   // full
    attn_probe<3, 8><<<dim3(896), dim3(256), 0, stream>>>(qkv, out);   // +PV
    attn_probe<2,16><<<dim3(896), dim3(256), 0, stream>>>(qkv, out);   // +softmax
    attn_probe<1,32><<<dim3(896), dim3(256), 0, stream>>>(qkv, out);   // loads
}

// Round 8
// 434.775 us; speedup vs baseline: 2.2702x; 2.2702x over previous
//
#include <hip/hip_runtime.h>
#include <hip/hip_bf16.h>

#define HWSZ 12544   // 112*112
#define WDIM 112
#define CIN  128
#define NPIX 25088   // B*HWSZ, B=2
#define VTROW 6272   // 112*56 = one (b,parity,ch) plane of vt (hw>>1 indexed)
#define VTOFF (2 * (size_t)NPIX * 64)   // vt base in qkv (u16 units)

typedef __attribute__((ext_vector_type(8))) short          short8;
typedef __attribute__((ext_vector_type(4))) float          float4v;
typedef __attribute__((ext_vector_type(4))) unsigned short ushort4v;

#define AS1 __attribute__((address_space(1)))
#define AS3 __attribute__((address_space(3)))

__device__ __forceinline__ void gload_lds16(const void* g, void* l) {
    __builtin_amdgcn_global_load_lds((const AS1 unsigned int*)g,
                                     (AS3 unsigned int*)l, 16, 0, 0);
}

// keep values live without cost (rule #17)
__device__ __forceinline__ void sinkf(float a, float b, float c, float d) {
    asm volatile("" :: "v"(a), "v"(b), "v"(c), "v"(d));
}
__device__ __forceinline__ void sink4(float4v v) { sinkf(v[0], v[1], v[2], v[3]); }
__device__ __forceinline__ void sink8(short8 v) {
    float4v f = __builtin_bit_cast(float4v, v);
    sink4(f);
}

// NATTEN window start for K=7, D=2
__device__ __forceinline__ int window_start7x2(int idx, int L) {
    int ni = idx - 6;
    int imodd = idx & 1;
    int a = (L >> 1) << 1;
    int bb = L - a;
    int right = (imodd < bb) ? (L - bb + imodd - 12) : (a + imodd - 14);
    if (ni < 0) return imodd;
    if (idx + 6 >= L) return right;
    return ni;
}

__device__ __forceinline__ unsigned short f2bf(float f) {
    __hip_bfloat16 h = __float2bfloat16(f);
    return *(unsigned short*)&h;
}

// ---------------------------------------------------------------------------
// Projection GEMM — XCD-ALIGNED remap. R6 proved attn's load phase (82% of
// its time) runs at fabric BW (~8 TB/s) because proj wrote K/V/Q from
// round-robin XCDs while attn reads h-banded (XCD k owns h in [14k,14k+14)).
// Remap: tile covering h-band k dispatches at bx%8 == k, so producer and
// consumer share an L2. Bucket boundaries from xcd(t) = (64t+32)/1568.
// Pure permutation of identical work; 8 idle pad blocks. grid 400.
// ---------------------------------------------------------------------------
__global__ __launch_bounds__(256) void proj_mfma(
    const float* __restrict__ x,
    const float* __restrict__ Wq, const float* __restrict__ bq,
    const float* __restrict__ Wk, const float* __restrict__ bk,
    const float* __restrict__ Wv, const float* __restrict__ bv,
    unsigned short* __restrict__ qbuf)
{
    __shared__ __align__(16) unsigned short wsb[3][64][136];
    __shared__ __align__(16) unsigned short trans[64 * 80];

    // ---- XCD-aligned tile remap
    const int xk = blockIdx.x & 7, j = blockIdx.x >> 3;
    const int S0[8] = {0, 24, 49, 73, 98, 122, 147, 171};
    const int SZ[8] = {24, 25, 24, 25, 24, 25, 24, 25};
    int tile;
    if (j < SZ[xk])           tile = S0[xk] + j;             // b = 0 half
    else if (j < 2 * SZ[xk])  tile = 196 + S0[xk] + (j - SZ[xk]);  // b = 1
    else return;                                             // pad block

    const int t = threadIdx.x, lane = t & 63, wv = t >> 6, quad = lane >> 4;
    const int col = lane & 15;

    const int pix0 = tile * 64;
    const int b    = tile / 196;
    const int hw0  = pix0 - b * HWSZ;
    const float* xb = x + (size_t)b * CIN * HWSZ;

    #pragma unroll
    for (int m = 0; m < 3; ++m) {
        const float* Wm = (m == 0) ? Wq : (m == 1) ? Wk : Wv;
        #pragma unroll
        for (int i = 0; i < 8; ++i) {
            int u = t + 256 * i;
            int o = u >> 5, cq = (u & 31) * 4;
            float4 w4 = *(const float4*)&Wm[o * 128 + cq];
            ushort4v s4 = { f2bf(w4.x), f2bf(w4.y), f2bf(w4.z), f2bf(w4.w) };
            *(ushort4v*)&wsb[m][o][cq] = s4;
        }
    }

    const int hwpx = hw0 + wv * 16 + col;
    short8 af[4];
    #pragma unroll
    for (int kc = 0; kc < 4; ++kc) {
        #pragma unroll
        for (int jj = 0; jj < 8; ++jj) {
            int c = kc * 32 + quad * 8 + jj;
            af[kc][jj] = (short)f2bf(xb[(size_t)c * HWSZ + hwpx]);
        }
    }
    __syncthreads();

    float4v acc[3][4];
    #pragma unroll
    for (int m = 0; m < 3; ++m)
        #pragma unroll
        for (int nt = 0; nt < 4; ++nt)
            acc[m][nt] = (float4v){0, 0, 0, 0};

    #pragma unroll
    for (int kc = 0; kc < 4; ++kc) {
        #pragma unroll
        for (int m = 0; m < 3; ++m) {
            #pragma unroll
            for (int nt = 0; nt < 4; ++nt) {
                short8 bfv = *(const short8*)&wsb[m][nt * 16 + col][kc * 32 + quad * 8];
                acc[m][nt] = __builtin_amdgcn_mfma_f32_16x16x32_bf16(af[kc], bfv, acc[m][nt], 0, 0, 0);
            }
        }
    }
    __syncthreads();

    #pragma unroll
    for (int m = 0; m < 2; ++m) {
        const float scale = (m == 0) ? 0.125f : 1.0f;
        const float* bm = (m == 0) ? bq : bk;
        #pragma unroll
        for (int nt = 0; nt < 4; ++nt) {
            float bias = bm[nt * 16 + col];
            #pragma unroll
            for (int r = 0; r < 4; ++r) {
                int px = wv * 16 + quad * 4 + r;
                trans[px * 80 + nt * 16 + col] = f2bf((acc[m][nt][r] + bias) * scale);
            }
        }
        __syncthreads();
        unsigned short* outm = qbuf + (size_t)m * NPIX * 64;
        const int tpx = t >> 2, chunk = t & 3;
        const unsigned short* src = &trans[tpx * 80 + chunk * 16];
        unsigned short* dst = outm + (size_t)(pix0 + tpx) * 64 + chunk * 16;
        *(short8*)(dst)     = *(const short8*)(src);
        *(short8*)(dst + 8) = *(const short8*)(src + 8);
        __syncthreads();
    }

    {
        #pragma unroll
        for (int nt = 0; nt < 4; ++nt) {
            int ch = nt * 16 + col;
            float bias = bv[ch];
            #pragma unroll
            for (int r = 0; r < 4; ++r) {
                int px = wv * 16 + quad * 4 + r;
                trans[ch * 80 + (px & 1) * 40 + (px >> 1)] = f2bf(acc[2][nt][r] + bias);
            }
        }
        __syncthreads();
        unsigned short* vt = qbuf + VTOFF;
        const int ch = t >> 2, parity = (t >> 1) & 1, half = t & 1;
        const unsigned short* src = &trans[ch * 80 + parity * 40 + half * 16];
        unsigned short* dst = vt + (size_t)((b * 2 + parity) * 64 + ch) * VTROW
                            + (hw0 >> 1) + half * 16;
        *(short8*)(dst)     = *(const short8*)(src);
        *(short8*)(dst + 8) = *(const short8*)(src + 8);
    }
}

// ---------------------------------------------------------------------------
// Attention body (unchanged from R6). MODE 0 full; MODE 1 loads-only probe.
// ---------------------------------------------------------------------------
template<int MODE>
__device__ __forceinline__ void attn_body_t(
    const unsigned short* __restrict__ qkv, float* __restrict__ out, int bx)
{
    __shared__ __align__(16) unsigned char slab[4][14336];
    __shared__ __align__(16) float sums_lds[2][2][16];

    const int tid  = threadIdx.x;
    const int lane = tid & 63, wid = tid >> 6;
    const int g    = wid & 1;
    const int vh   = wid >> 1;
    const int quad = lane >> 4, col = lane & 15;

    const int xcd  = bx & 7;
    const int idx  = bx >> 3;
    const int h    = xcd * 14 + (idx >> 3);
    const int b    = (idx >> 2) & 1;
    const int sub  = idx & 3;
    const int pb   = (sub < 3) ? sub * 16 : 40;

    const int hs  = window_start7x2(h, WDIM);
    const int ws0 = window_start7x2(2 * pb + g, WDIM);
    const int cb0 = (ws0 >> 1) & ~7;
    const int pixbase = b * HWSZ;

    const unsigned short* qg = qkv;
    const unsigned short* kg = qkv + (size_t)NPIX * 64;
    const unsigned short* vt = qkv + VTOFF + (size_t)(b * 2 + g) * 64 * VTROW;

    unsigned short* ps_g   = (unsigned short*)slab[g];
    unsigned char*  myslab = slab[wid];

    const int qpix = pixbase + h * WDIM + 2 * (pb + col) + g;
    short8 af0 = *(const short8*)(qg + (size_t)qpix * 64 + quad * 8);
    short8 af1 = *(const short8*)(qg + (size_t)qpix * 64 + 32 + quad * 8);

    int cbr[4];
    #pragma unroll
    for (int r = 0; r < 4; ++r)
        cbr[r] = (window_start7x2(2 * (pb + quad * 4 + r) + g, WDIM) >> 1) - cb0;

    int rowoff[7];
    #pragma unroll
    for (int kc = 0; kc < 7; ++kc) {
        int u8 = kc * 32 + quad * 8;
        rowoff[kc] = (hs + 2 * (u8 >> 5)) * 56 + cb0 + (u8 & 31);
    }
    short8 vpre[7][2];
    #pragma unroll
    for (int kc = 0; kc < 7; ++kc)
        #pragma unroll
        for (int ntl = 0; ntl < 2; ++ntl)
            vpre[kc][ntl] = *(const short8*)
                (vt + (size_t)(vh * 32 + ntl * 16 + col) * VTROW + rowoff[kc]);

    #pragma unroll
    for (int ntl = 0; ntl < 7; ++ntl) {
        int u = (vh * 7 + ntl) * 16 + col;
        int i = u >> 5, c = u & 31;
        int kw = 2 * (cb0 + c) + g; kw = (kw > 111) ? 111 : kw;
        int kp = pixbase + (hs + 2 * i) * WDIM + kw;
        const unsigned short* gs = kg + (size_t)kp * 64 + quad * 8;
        gload_lds16(gs,      myslab + ntl * 2048);
        gload_lds16(gs + 32, myslab + ntl * 2048 + 1024);
    }

    asm volatile("s_waitcnt vmcnt(0)" ::: "memory");
    __builtin_amdgcn_sched_barrier(0);

    if constexpr (MODE == 1) {
        sink8(af0); sink8(af1);
        #pragma unroll
        for (int kc = 0; kc < 7; ++kc) { sink8(vpre[kc][0]); sink8(vpre[kc][1]); }
        return;
    }

    float4v S[7];
    #pragma unroll
    for (int ntl = 0; ntl < 7; ++ntl) {
        short8 b0 = *(const short8*)(myslab + ntl * 2048 + lane * 16);
        short8 b1 = *(const short8*)(myslab + ntl * 2048 + 1024 + lane * 16);
        float4v a = {0, 0, 0, 0};
        a = __builtin_amdgcn_mfma_f32_16x16x32_bf16(af0, b0, a, 0, 0, 0);
        a = __builtin_amdgcn_mfma_f32_16x16x32_bf16(af1, b1, a, 0, 0, 0);
        int u = (vh * 7 + ntl) * 16 + col;
        int c = u & 31;
        bool colok = (cb0 + c <= 55);
        #pragma unroll
        for (int r = 0; r < 4; ++r) {
            bool valid = colok && ((unsigned)(c - cbr[r]) < 7u);
            S[ntl][r] = valid ? a[r] : -1e30f;
        }
    }

    float psum[4];
    #pragma unroll
    for (int r = 0; r < 4; ++r) {
        float sum = 0.0f;
        #pragma unroll
        for (int ntl = 0; ntl < 7; ++ntl) {
            float e = __expf(S[ntl][r]);
            S[ntl][r] = e;
            sum += e;
        }
        #pragma unroll
        for (int msk = 1; msk < 16; msk <<= 1)
            sum += __shfl_xor(sum, msk, 64);
        psum[r] = sum;
    }

    __syncthreads();

    #pragma unroll
    for (int r = 0; r < 4; ++r) {
        int row = quad * 4 + r;
        #pragma unroll
        for (int ntl = 0; ntl < 7; ++ntl)
            ps_g[row * 232 + (vh * 7 + ntl) * 16 + col] = f2bf(S[ntl][r]);
    }
    if (col == 0) {
        #pragma unroll
        for (int r = 0; r < 4; ++r)
            sums_lds[g][vh][quad * 4 + r] = psum[r];
    }
    __syncthreads();

    float rinv[4];
    #pragma unroll
    for (int r = 0; r < 4; ++r) {
        int row = quad * 4 + r;
        rinv[r] = 1.0f / (sums_lds[g][0][row] + sums_lds[g][1][row]);
    }

    float4v O[2] = {{0,0,0,0},{0,0,0,0}};
    #pragma unroll
    for (int kc = 0; kc < 7; ++kc) {
        short8 pa = *(const short8*)&ps_g[col * 232 + kc * 32 + quad * 8];
        #pragma unroll
        for (int ntl = 0; ntl < 2; ++ntl)
            O[ntl] = __builtin_amdgcn_mfma_f32_16x16x32_bf16(pa, vpre[kc][ntl], O[ntl], 0, 0, 0);
    }

    float* lds_out = (float*)slab[2];
    #pragma unroll
    for (int ntl = 0; ntl < 2; ++ntl) {
        int ch = vh * 32 + ntl * 16 + col;
        #pragma unroll
        for (int r = 0; r < 4; ++r)
            lds_out[ch * 36 + 2 * (quad * 4 + r) + g] = O[ntl][r] * rinv[r];
    }
    __syncthreads();

    {
        const int ch = tid >> 2, q4 = tid & 3;
        float* ob = out + (size_t)(b * 64 + ch) * HWSZ + h * WDIM + 2 * pb + q4 * 8;
        const float* src = &lds_out[ch * 36 + q4 * 8];
        *(float4*)(ob)     = *(const float4*)(src);
        *(float4*)(ob + 4) = *(const float4*)(src + 4);
    }
}

__global__ __launch_bounds__(256) void attn_mfma(
    const unsigned short* __restrict__ qkv, float* __restrict__ out)
{
    attn_body_t<0>(qkv, out, blockIdx.x);
}

// DIAGNOSTIC probes (verdict on the XCD co-location fix; stripped next round)
template<int MODE, int REPS>
__global__ __launch_bounds__(256) void attn_probe(
    const unsigned short* __restrict__ qkv, float* __restrict__ out)
{
    for (int rep = 0; rep < REPS; ++rep) {
        const unsigned short* qr = qkv;
        float* orr = out;
        asm volatile("" : "+v"(qr), "+v"(orr) :: "memory");
        attn_body_t<MODE>(qr, orr, blockIdx.x);
        __syncthreads();
    }
}

// ---------------------------------------------------------------------------
extern "C" void kernel_launch(void* const* d_in, const int* in_sizes, int n_in,
                              void* d_out, int out_size, void* d_ws, size_t ws_size,
                              hipStream_t stream) {
    const float* x  = (const float*)d_in[0];
    const float* Wq = (const float*)d_in[1];
    const float* bq = (const float*)d_in[2];
    const float* Wk = (const float*)d_in[3];
    const float* bk = (const float*)d_in[4];
    const float* Wv = (const float*)d_in[5];
    const float* bv = (const float*)d_in[6];
    float* out = (float*)d_out;

    unsigned short* qkv = (unsigned short*)d_ws;

    // real pipeline (proj now XCD-aligned with attn's h-bands)
    proj_mfma<<<dim3(400), dim3(256), 0, stream>>>(x, Wq, bq, Wk, bk, Wv, bv, qkv);
    attn_mfma<<<dim3(896), dim3(256), 0, stream>>>(qkv, out);

    // verdict probes: did co-location collapse the load phase?
    attn_probe<0, 8><<<dim3(896), dim3(256), 0, stream>>>(qkv, out);   // full
    attn_probe<1,16><<<dim3(896), dim3(256), 0, stream>>>(qkv, out);   // loads
}